// Round 1
// baseline (1330.805 us; speedup 1.0000x reference)
//
#include <hip/hip_runtime.h>
#include <hip/hip_bf16.h>

typedef unsigned int uint32;

namespace {
constexpr int N0c = 50000;
constexpr int N1c = 150000;
constexpr int N2c = 100000;
constexpr int NTc = N0c + N1c + N2c;   // 300000 rows of xj (concat)
constexpr int E0c = 800000;
constexpr int E1c = 300000;
constexpr int E2c = 300000;
constexpr int ETc = E0c + E1c + E2c;   // 1.4M edges
constexpr int D = 256;
}

__device__ __forceinline__ unsigned short f2bf_bits(float f) {
  __hip_bfloat16 h = __float2bfloat16(f);
  union { __hip_bfloat16 h; unsigned short u; } cv;
  cv.h = h;
  return cv.u;
}
__device__ __forceinline__ float bf_bits2f(unsigned short u) {
  return __uint_as_float(((uint32)u) << 16);
}

// ---- init: ai = a1_b, AJ = a2_b, counts = 0 --------------------------------
__global__ void init_kernel(float* __restrict__ ai, float* __restrict__ AJ,
                            int* __restrict__ counts,
                            const float* __restrict__ a1_b,
                            const float* __restrict__ a2_b) {
  int i = blockIdx.x * blockDim.x + threadIdx.x;
  if (i < NTc) AJ[i] = a2_b[0];
  if (i < N0c) { ai[i] = a1_b[0]; counts[i] = 0; }
}

// ---- fused GEMM: Y = relu(X @ W^T + b), att_out[m] += Y[m,:] . av ----------
// X [M,256] row-major, W [256,256] row-major (torch Linear weight)
// 64x64 tile, BK=16, 256 threads, 4x4 acc per thread.
__global__ __launch_bounds__(256)
void gemm_relu_att(const float* __restrict__ X, const float* __restrict__ W,
                   const float* __restrict__ Bb, const float* __restrict__ av,
                   float* __restrict__ att_out,
                   float* __restrict__ Yf, unsigned short* __restrict__ Yh,
                   int M) {
  __shared__ float As[16][68];   // [k][m], pad 68: 16B-aligned rows, 2-way max
  __shared__ float Bs[16][68];   // [k][n]
  const int t = threadIdx.x;
  const int m0 = blockIdx.x * 64;
  const int n0 = blockIdx.y * 64;
  const int tx = t & 15, ty = t >> 4;
  const int lrow = t >> 2;          // 0..63
  const int lk = (t & 3) << 2;      // 0,4,8,12
  const bool mvalid = (m0 + lrow) < M;
  const float* Xp = X + (size_t)(m0 + lrow) * D + lk;
  const float* Wp = W + (size_t)(n0 + lrow) * D + lk;

  float acc[4][4] = {};
  for (int k0 = 0; k0 < D; k0 += 16) {
    float4 a = mvalid ? *(const float4*)(Xp + k0) : make_float4(0.f, 0.f, 0.f, 0.f);
    float4 b = *(const float4*)(Wp + k0);
    __syncthreads();
    As[lk + 0][lrow] = a.x; As[lk + 1][lrow] = a.y;
    As[lk + 2][lrow] = a.z; As[lk + 3][lrow] = a.w;
    Bs[lk + 0][lrow] = b.x; Bs[lk + 1][lrow] = b.y;
    Bs[lk + 2][lrow] = b.z; Bs[lk + 3][lrow] = b.w;
    __syncthreads();
#pragma unroll
    for (int k = 0; k < 16; ++k) {
      float4 a4 = *(const float4*)&As[k][ty << 2];
      float4 b4 = *(const float4*)&Bs[k][tx << 2];
      float am[4] = {a4.x, a4.y, a4.z, a4.w};
      float bn[4] = {b4.x, b4.y, b4.z, b4.w};
#pragma unroll
      for (int i = 0; i < 4; ++i)
#pragma unroll
        for (int j = 0; j < 4; ++j)
          acc[i][j] = fmaf(am[i], bn[j], acc[i][j]);
    }
  }

  float bj[4], aw[4];
#pragma unroll
  for (int j = 0; j < 4; ++j) {
    bj[j] = Bb[n0 + (tx << 2) + j];
    aw[j] = av[n0 + (tx << 2) + j];
  }
#pragma unroll
  for (int i = 0; i < 4; ++i) {
    int m = m0 + (ty << 2) + i;
    float y[4];
#pragma unroll
    for (int j = 0; j < 4; ++j) {
      float v = acc[i][j] + bj[j];
      y[j] = v > 0.f ? v : 0.f;
    }
    float p = y[0] * aw[0] + y[1] * aw[1] + y[2] * aw[2] + y[3] * aw[3];
    p += __shfl_xor(p, 1);
    p += __shfl_xor(p, 2);
    p += __shfl_xor(p, 4);
    p += __shfl_xor(p, 8);
    if (m < M) {
      if (Yf) {
        *(float4*)(Yf + (size_t)m * D + n0 + (tx << 2)) =
            make_float4(y[0], y[1], y[2], y[3]);
      } else {
        ushort4 o;
        o.x = f2bf_bits(y[0]); o.y = f2bf_bits(y[1]);
        o.z = f2bf_bits(y[2]); o.w = f2bf_bits(y[3]);
        *(ushort4*)(Yh + (size_t)m * D + n0 + (tx << 2)) = o;
      }
      if (tx == 0) atomicAdd(&att_out[m], p);
    }
  }
}

// ---- CSR build -------------------------------------------------------------
__global__ void hist_kernel(const int* __restrict__ r0, const int* __restrict__ r1,
                            const int* __restrict__ r2, int* __restrict__ counts) {
  int i = blockIdx.x * blockDim.x + threadIdx.x;
  if (i >= ETc) return;
  int row;
  if (i < E0c) row = r0[i];
  else if (i < E0c + E1c) row = r1[i - E0c];
  else row = r2[i - E0c - E1c];
  atomicAdd(&counts[row], 1);
}

__global__ __launch_bounds__(1024)
void scan_kernel(const int* __restrict__ counts, int* __restrict__ row_start,
                 int* __restrict__ fill) {
  __shared__ int sums[1024];
  const int n = N0c;
  const int t = threadIdx.x;
  const int chunk = (n + 1023) / 1024;  // 49
  int begin = t * chunk; if (begin > n) begin = n;
  int end = begin + chunk; if (end > n) end = n;
  int s = 0;
  for (int i = begin; i < end; ++i) s += counts[i];
  sums[t] = s;
  __syncthreads();
  for (int off = 1; off < 1024; off <<= 1) {
    int v = (t >= off) ? sums[t - off] : 0;
    __syncthreads();
    sums[t] += v;
    __syncthreads();
  }
  int run = sums[t] - s;  // exclusive prefix
  for (int i = begin; i < end; ++i) {
    row_start[i] = run; fill[i] = run; run += counts[i];
  }
  if (t == 1023) row_start[n] = sums[1023];
}

__global__ void scatter_kernel(const int* __restrict__ r0, const int* __restrict__ c0,
                               const int* __restrict__ r1, const int* __restrict__ c1,
                               const int* __restrict__ r2, const int* __restrict__ c2,
                               int* __restrict__ fill, int* __restrict__ edge_dst) {
  int i = blockIdx.x * blockDim.x + threadIdx.x;
  if (i >= ETc) return;
  int row, col;
  if (i < E0c) { row = r0[i]; col = c0[i]; }
  else if (i < E0c + E1c) { int j = i - E0c; row = r1[j]; col = N0c + c1[j]; }
  else { int j = i - E0c - E1c; row = r2[j]; col = N0c + N1c + c2[j]; }
  int pos = atomicAdd(&fill[row], 1);
  edge_dst[pos] = col;
}

// ---- aggregation: out[n] = xi0[n] + sum_e sigmoid(ai[n]+AJ[c]) * XJ[c] -----
__global__ __launch_bounds__(64)
void aggregate_kernel(const float* __restrict__ xi0,
                      const unsigned short* __restrict__ XJ,
                      const float* __restrict__ ai, const float* __restrict__ AJ,
                      const int* __restrict__ row_start,
                      const int* __restrict__ edge_dst,
                      float* __restrict__ out) {
  const int n = blockIdx.x;
  const int l = threadIdx.x;
  const float4* xi4 = (const float4*)(xi0 + (size_t)n * D);
  float4 acc = xi4[l];
  const float air = ai[n];
  const int s = row_start[n], e = row_start[n + 1];
  const ushort4* xj4 = (const ushort4*)XJ;
  int i = s;
  for (; i + 1 < e; i += 2) {
    int c0 = edge_dst[i], c1 = edge_dst[i + 1];
    float aj0 = AJ[c0], aj1 = AJ[c1];
    ushort4 v0 = xj4[(size_t)c0 * 64 + l];
    ushort4 v1 = xj4[(size_t)c1 * 64 + l];
    float att0 = 1.f / (1.f + __expf(-(air + aj0)));
    float att1 = 1.f / (1.f + __expf(-(air + aj1)));
    acc.x = fmaf(att0, bf_bits2f(v0.x), acc.x);
    acc.y = fmaf(att0, bf_bits2f(v0.y), acc.y);
    acc.z = fmaf(att0, bf_bits2f(v0.z), acc.z);
    acc.w = fmaf(att0, bf_bits2f(v0.w), acc.w);
    acc.x = fmaf(att1, bf_bits2f(v1.x), acc.x);
    acc.y = fmaf(att1, bf_bits2f(v1.y), acc.y);
    acc.z = fmaf(att1, bf_bits2f(v1.z), acc.z);
    acc.w = fmaf(att1, bf_bits2f(v1.w), acc.w);
  }
  if (i < e) {
    int c0 = edge_dst[i];
    float att0 = 1.f / (1.f + __expf(-(air + AJ[c0])));
    ushort4 v0 = xj4[(size_t)c0 * 64 + l];
    acc.x = fmaf(att0, bf_bits2f(v0.x), acc.x);
    acc.y = fmaf(att0, bf_bits2f(v0.y), acc.y);
    acc.z = fmaf(att0, bf_bits2f(v0.z), acc.z);
    acc.w = fmaf(att0, bf_bits2f(v0.w), acc.w);
  }
  ((float4*)(out + (size_t)n * D))[l] = acc;
}

extern "C" void kernel_launch(void* const* d_in, const int* in_sizes, int n_in,
                              void* d_out, int out_size, void* d_ws, size_t ws_size,
                              hipStream_t stream) {
  const float* x0 = (const float*)d_in[0];
  const float* x1 = (const float*)d_in[1];
  const float* x2 = (const float*)d_in[2];
  const int* rows0 = (const int*)d_in[3];
  const int* cols0 = (const int*)d_in[4];
  const int* rows1 = (const int*)d_in[5];
  const int* cols1 = (const int*)d_in[6];
  const int* rows2 = (const int*)d_in[7];
  const int* cols2 = (const int*)d_in[8];
  const float* W1 = (const float*)d_in[9];
  const float* b1 = (const float*)d_in[10];
  const float* W2 = (const float*)d_in[11];
  const float* b2 = (const float*)d_in[12];
  const float* W3 = (const float*)d_in[13];
  const float* b3 = (const float*)d_in[14];
  const float* W4 = (const float*)d_in[15];
  const float* b4 = (const float*)d_in[16];
  const float* a1_w = (const float*)d_in[17];
  const float* a1_b = (const float*)d_in[18];
  const float* a2_w = (const float*)d_in[19];
  const float* a2_b = (const float*)d_in[20];
  float* out = (float*)d_out;

  char* ws = (char*)d_ws;
  size_t off = 0;
  auto alloc = [&](size_t bytes) -> void* {
    void* p = ws + off;
    off = (off + bytes + 255) & ~(size_t)255;
    return p;
  };
  unsigned short* XJ = (unsigned short*)alloc((size_t)NTc * D * 2);  // bf16 xj concat
  float* xi0 = (float*)alloc((size_t)N0c * D * 4);
  float* AJ = (float*)alloc((size_t)NTc * 4);
  float* ai = (float*)alloc((size_t)N0c * 4);
  int* counts = (int*)alloc((size_t)N0c * 4);
  int* row_start = (int*)alloc((size_t)(N0c + 1) * 4);
  int* fill = (int*)alloc((size_t)N0c * 4);
  int* edge_dst = (int*)alloc((size_t)ETc * 4);
  (void)ws_size; (void)in_sizes; (void)n_in; (void)out_size;

  hipLaunchKernelGGL(init_kernel, dim3((NTc + 255) / 256), dim3(256), 0, stream,
                     ai, AJ, counts, a1_b, a2_b);
  // CSR build can overlap-order with GEMMs on the stream (serialized anyway)
  hipLaunchKernelGGL(hist_kernel, dim3((ETc + 255) / 256), dim3(256), 0, stream,
                     rows0, rows1, rows2, counts);
  hipLaunchKernelGGL(scan_kernel, dim3(1), dim3(1024), 0, stream,
                     counts, row_start, fill);
  hipLaunchKernelGGL(scatter_kernel, dim3((ETc + 255) / 256), dim3(256), 0, stream,
                     rows0, cols0, rows1, cols1, rows2, cols2, fill, edge_dst);

  hipLaunchKernelGGL(gemm_relu_att, dim3((N0c + 63) / 64, 4), dim3(256), 0, stream,
                     x0, W1, b1, a1_w, ai, xi0, (unsigned short*)nullptr, N0c);
  hipLaunchKernelGGL(gemm_relu_att, dim3((N0c + 63) / 64, 4), dim3(256), 0, stream,
                     x0, W2, b2, a2_w, AJ, (float*)nullptr, XJ, N0c);
  hipLaunchKernelGGL(gemm_relu_att, dim3((N1c + 63) / 64, 4), dim3(256), 0, stream,
                     x1, W3, b3, a2_w, AJ + N0c, (float*)nullptr,
                     XJ + (size_t)N0c * D, N1c);
  hipLaunchKernelGGL(gemm_relu_att, dim3((N2c + 63) / 64, 4), dim3(256), 0, stream,
                     x2, W4, b4, a2_w, AJ + N0c + N1c, (float*)nullptr,
                     XJ + (size_t)(N0c + N1c) * D, N2c);

  hipLaunchKernelGGL(aggregate_kernel, dim3(N0c), dim3(64), 0, stream,
                     xi0, XJ, ai, AJ, row_start, edge_dst, out);
}

// Round 2
// 816.867 us; speedup vs baseline: 1.6292x; 1.6292x over previous
//
#include <hip/hip_runtime.h>
#include <hip/hip_bf16.h>

typedef unsigned short ushort_t;
typedef __bf16 bf16x8 __attribute__((ext_vector_type(8)));
typedef float f32x4 __attribute__((ext_vector_type(4)));
typedef unsigned short u16x8 __attribute__((ext_vector_type(8)));

namespace {
constexpr int N0c = 50000;
constexpr int N1c = 150000;
constexpr int N2c = 100000;
constexpr int NTc = N0c + N1c + N2c;   // 300000
constexpr int E0c = 800000;
constexpr int E1c = 300000;
constexpr int E2c = 300000;
constexpr int ETc = E0c + E1c + E2c;   // 1.4M
constexpr int D = 256;
constexpr int SCAN_BLOCKS = (N0c + 255) / 256;  // 196
}

__device__ __forceinline__ ushort_t f2b(float f) {
  return __builtin_bit_cast(ushort_t, (__bf16)f);
}
__device__ __forceinline__ float b2f(ushort_t u) {
  return __uint_as_float(((unsigned int)u) << 16);
}

#define GLDS16(gp, lp) __builtin_amdgcn_global_load_lds( \
    (const __attribute__((address_space(1))) void*)(gp), \
    (__attribute__((address_space(3))) void*)(lp), 16, 0, 0)

// ---- init: ai = a1_b, AJ = a2_b, counts = 0 --------------------------------
__global__ void init_kernel(float* __restrict__ ai, float* __restrict__ AJ,
                            int* __restrict__ counts,
                            const float* __restrict__ a1_b,
                            const float* __restrict__ a2_b) {
  int i = blockIdx.x * blockDim.x + threadIdx.x;
  if (i < NTc) AJ[i] = a2_b[0];
  if (i < N0c) { ai[i] = a1_b[0]; counts[i] = 0; }
}

// ---- W -> bf16, k-granule-major: Wt[(kg*256+col)*8 + j] = W[col*256+kg*8+j]
__global__ void wconv_kernel(const float* __restrict__ W1, const float* __restrict__ W2,
                             const float* __restrict__ W3, const float* __restrict__ W4,
                             ushort_t* __restrict__ Wt) {
  int layer = blockIdx.y;
  const float* W = layer == 0 ? W1 : layer == 1 ? W2 : layer == 2 ? W3 : W4;
  int g = blockIdx.x * 256 + threadIdx.x;   // 0..8191
  int kg = g >> 8, col = g & 255;
  const float* s = W + col * 256 + kg * 8;
  float4 f0 = *(const float4*)s;
  float4 f1 = *(const float4*)(s + 4);
  u16x8 h;
  h[0] = f2b(f0.x); h[1] = f2b(f0.y); h[2] = f2b(f0.z); h[3] = f2b(f0.w);
  h[4] = f2b(f1.x); h[5] = f2b(f1.y); h[6] = f2b(f1.z); h[7] = f2b(f1.w);
  *(u16x8*)(Wt + (size_t)layer * 65536 + (size_t)g * 8) = h;
}

// ---- MFMA GEMM: Y(bf16) = relu(X @ W^T + b); att_out[m] += Y[m,:].av -------
// BM=64 rows/block, BN=256 (full), BK=32, 256 threads (4 waves).
__global__ __launch_bounds__(256)
void gemm_mfma(const float* __restrict__ X, const ushort_t* __restrict__ Wt,
               const float* __restrict__ Bb, const float* __restrict__ av,
               float* __restrict__ att_out, ushort_t* __restrict__ Y, int M) {
  __shared__ ushort_t lds[2 * 1280 * 8];   // 40 KB: per buf: A 256 gran, B 1024 gran
  const int t = threadIdx.x;
  const int w = t >> 6, l = t & 63;
  const int lq = l >> 4, lr = l & 15;
  const int m0 = blockIdx.x * 64;

  // A staging mapping: thread -> (row=t>>2, kg=t&3); 32B coalesced per 4 thr
  const int srow = t >> 2, ssub = t & 3;
  const bool rowok = (m0 + srow) < M;
  const float* xp = X + (size_t)(m0 + srow) * D + ssub * 8;
  // swizzled A granule (write 2-way free, read conflict-free)
  const int ag = (ssub * 64 + (srow ^ (ssub << 2))) * 8;

  f32x4 acc[4][4];
#pragma unroll
  for (int i = 0; i < 4; ++i)
#pragma unroll
    for (int j = 0; j < 4; ++j)
#pragma unroll
      for (int r = 0; r < 4; ++r) acc[i][j][r] = 0.f;

  auto stageA_write = [&](int buf, float4 f0, float4 f1) {
    bf16x8 h;
    h[0] = (__bf16)f0.x; h[1] = (__bf16)f0.y; h[2] = (__bf16)f0.z; h[3] = (__bf16)f0.w;
    h[4] = (__bf16)f1.x; h[5] = (__bf16)f1.y; h[6] = (__bf16)f1.z; h[7] = (__bf16)f1.w;
    *(bf16x8*)(&lds[buf * 10240 + ag]) = h;
  };
  auto issueB = [&](int buf, int kk) {
    const char* src = (const char*)Wt + kk * 16384 + w * 4096 + l * 16;
    char* dst = (char*)lds + buf * 20480 + 4096 + w * 4096;
#pragma unroll
    for (int it = 0; it < 4; ++it) GLDS16(src + it * 1024, dst + it * 1024);
  };

  { // prologue: stage k-step 0 into buf 0
    float4 f0 = rowok ? *(const float4*)xp : make_float4(0, 0, 0, 0);
    float4 f1 = rowok ? *(const float4*)(xp + 4) : make_float4(0, 0, 0, 0);
    stageA_write(0, f0, f1);
    issueB(0, 0);
  }
#pragma unroll
  for (int kk = 0; kk < 8; ++kk) {
    const int buf = kk & 1;
    __syncthreads();
    float4 f0, f1;
    if (kk < 7) {  // issue next X loads + B direct-to-LDS before compute
      f0 = rowok ? *(const float4*)(xp + (kk + 1) * 32) : make_float4(0, 0, 0, 0);
      f1 = rowok ? *(const float4*)(xp + (kk + 1) * 32 + 4) : make_float4(0, 0, 0, 0);
      issueB(buf ^ 1, kk + 1);
    }
    const ushort_t* Al = &lds[buf * 10240];
    const ushort_t* Bl = &lds[buf * 10240 + 2048];
    bf16x8 bfr[4];
#pragma unroll
    for (int ni = 0; ni < 4; ++ni)
      bfr[ni] = *(const bf16x8*)(Bl + (lq * 256 + w * 64 + ni * 16 + lr) * 8);
#pragma unroll
    for (int mi = 0; mi < 4; ++mi) {
      bf16x8 afr = *(const bf16x8*)(Al + (lq * 64 + ((mi * 16 + lr) ^ (lq << 2))) * 8);
#pragma unroll
      for (int ni = 0; ni < 4; ++ni)
        acc[mi][ni] = __builtin_amdgcn_mfma_f32_16x16x32_bf16(afr, bfr[ni], acc[mi][ni], 0, 0, 0);
    }
    if (kk < 7) stageA_write(buf ^ 1, f0, f1);  // cvt+ds_write after MFMAs (load latency hidden)
  }
  __syncthreads();

  // epilogue: bias+relu, att dot (atomic), Y via LDS restage (coalesced bf16 store)
  float avv[4], bjv[4];
#pragma unroll
  for (int ni = 0; ni < 4; ++ni) {
    int c = w * 64 + ni * 16 + lr;
    avv[ni] = av[c]; bjv[ni] = Bb[c];
  }
#pragma unroll
  for (int mi = 0; mi < 4; ++mi) {
    float p[4] = {0.f, 0.f, 0.f, 0.f};
#pragma unroll
    for (int ni = 0; ni < 4; ++ni) {
#pragma unroll
      for (int r = 0; r < 4; ++r) {
        float y = acc[mi][ni][r] + bjv[ni];
        y = y > 0.f ? y : 0.f;
        p[r] += y * avv[ni];
        lds[(mi * 16 + lq * 4 + r) * 256 + (w * 64 + ni * 16 + lr)] = f2b(y);
      }
    }
#pragma unroll
    for (int r = 0; r < 4; ++r) {
      float q = p[r];
      q += __shfl_xor(q, 1); q += __shfl_xor(q, 2);
      q += __shfl_xor(q, 4); q += __shfl_xor(q, 8);
      int row = m0 + mi * 16 + lq * 4 + r;
      if (lr == 0 && row < M) atomicAdd(att_out + row, q);
    }
  }
  __syncthreads();
#pragma unroll
  for (int j = 0; j < 8; ++j) {
    int idx = t * 64 + j * 8;        // ushort index in 64x256 tile
    int grow = idx >> 8;
    if (m0 + grow < M)
      *(u16x8*)(Y + (size_t)(m0 + grow) * D + (idx & 255)) = *(const u16x8*)(&lds[idx]);
  }
}

// ---- CSR build -------------------------------------------------------------
__global__ void hist_kernel(const int* __restrict__ r0, const int* __restrict__ r1,
                            const int* __restrict__ r2, int* __restrict__ counts) {
  int i = blockIdx.x * blockDim.x + threadIdx.x;
  if (i >= ETc) return;
  int row;
  if (i < E0c) row = r0[i];
  else if (i < E0c + E1c) row = r1[i - E0c];
  else row = r2[i - E0c - E1c];
  atomicAdd(&counts[row], 1);
}

__device__ __forceinline__ int block_incl_scan(int v, int t) {
  int x = v;
#pragma unroll
  for (int off = 1; off < 64; off <<= 1) {
    int y = __shfl_up(x, off);
    if ((t & 63) >= off) x += y;
  }
  __shared__ int wls[4];
  if ((t & 63) == 63) wls[t >> 6] = x;
  __syncthreads();
  int add = 0;
#pragma unroll
  for (int ww = 0; ww < 4; ++ww) add += (ww < (t >> 6)) ? wls[ww] : 0;
  return x + add;
}

__global__ void blocksum_kernel(const int* __restrict__ counts, int* __restrict__ bsum) {
  int b = blockIdx.x, t = threadIdx.x;
  int i = b * 256 + t;
  int v = (i < N0c) ? counts[i] : 0;
#pragma unroll
  for (int off = 1; off < 64; off <<= 1) v += __shfl_xor(v, off);
  __shared__ int ws_[4];
  if ((t & 63) == 0) ws_[t >> 6] = v;
  __syncthreads();
  if (t == 0) bsum[b] = ws_[0] + ws_[1] + ws_[2] + ws_[3];
}

__global__ void scantop_kernel(const int* __restrict__ bsum, int* __restrict__ boff,
                               int* __restrict__ row_start) {
  int t = threadIdx.x;
  int v = (t < SCAN_BLOCKS) ? bsum[t] : 0;
  int x = block_incl_scan(v, t);
  if (t < SCAN_BLOCKS) boff[t] = x - v;
  if (t == 0) row_start[N0c] = ETc;
}

__global__ void emit_kernel(const int* __restrict__ counts, const int* __restrict__ boff,
                            int* __restrict__ row_start, int* __restrict__ fill) {
  int b = blockIdx.x, t = threadIdx.x, i = b * 256 + t;
  int v = (i < N0c) ? counts[i] : 0;
  int x = block_incl_scan(v, t);
  int ex = x - v + boff[b];
  if (i < N0c) { row_start[i] = ex; fill[i] = ex; }
}

__global__ void scatter_kernel(const int* __restrict__ r0, const int* __restrict__ c0,
                               const int* __restrict__ r1, const int* __restrict__ c1,
                               const int* __restrict__ r2, const int* __restrict__ c2,
                               int* __restrict__ fill, int* __restrict__ edge_dst) {
  int i = blockIdx.x * blockDim.x + threadIdx.x;
  if (i >= ETc) return;
  int row, col;
  if (i < E0c) { row = r0[i]; col = c0[i]; }
  else if (i < E0c + E1c) { int j = i - E0c; row = r1[j]; col = N0c + c1[j]; }
  else { int j = i - E0c - E1c; row = r2[j]; col = N0c + N1c + c2[j]; }
  int pos = atomicAdd(&fill[row], 1);
  edge_dst[pos] = col;
}

// ---- aggregation: half-wave per edge, ushort8 (16B) loads, 4 edges in flight
__global__ __launch_bounds__(64)
void aggregate_kernel(const ushort_t* __restrict__ XI0, const ushort_t* __restrict__ XJ,
                      const float* __restrict__ ai, const float* __restrict__ AJ,
                      const int* __restrict__ row_start, const int* __restrict__ edge_dst,
                      float* __restrict__ out) {
  const int n = blockIdx.x;
  const int l = threadIdx.x;
  const int h = l >> 5, cc = l & 31;
  const float air = ai[n];
  const int s = row_start[n], e = row_start[n + 1];
  const u16x8* XJ8 = (const u16x8*)XJ;
  float acc[8] = {0.f, 0.f, 0.f, 0.f, 0.f, 0.f, 0.f, 0.f};
  int idx = s + h;
  for (; idx + 2 < e; idx += 4) {
    int c0 = edge_dst[idx], c1 = edge_dst[idx + 2];
    float z0 = air + AJ[c0], z1 = air + AJ[c1];
    u16x8 v0 = XJ8[(size_t)c0 * 32 + cc];
    u16x8 v1 = XJ8[(size_t)c1 * 32 + cc];
    float a0 = 1.f / (1.f + __expf(-z0));
    float a1 = 1.f / (1.f + __expf(-z1));
#pragma unroll
    for (int k = 0; k < 8; ++k) acc[k] = fmaf(a0, b2f(v0[k]), acc[k]);
#pragma unroll
    for (int k = 0; k < 8; ++k) acc[k] = fmaf(a1, b2f(v1[k]), acc[k]);
  }
  for (; idx < e; idx += 2) {
    int c0 = edge_dst[idx];
    float z0 = air + AJ[c0];
    u16x8 v0 = XJ8[(size_t)c0 * 32 + cc];
    float a0 = 1.f / (1.f + __expf(-z0));
#pragma unroll
    for (int k = 0; k < 8; ++k) acc[k] = fmaf(a0, b2f(v0[k]), acc[k]);
  }
#pragma unroll
  for (int k = 0; k < 8; ++k) acc[k] += __shfl_xor(acc[k], 32);
  if (l < 32) {
    u16x8 xv = ((const u16x8*)XI0)[(size_t)n * 32 + cc];
    float4 o0, o1;
    o0.x = acc[0] + b2f(xv[0]); o0.y = acc[1] + b2f(xv[1]);
    o0.z = acc[2] + b2f(xv[2]); o0.w = acc[3] + b2f(xv[3]);
    o1.x = acc[4] + b2f(xv[4]); o1.y = acc[5] + b2f(xv[5]);
    o1.z = acc[6] + b2f(xv[6]); o1.w = acc[7] + b2f(xv[7]);
    float4* op = (float4*)(out + (size_t)n * D) + cc * 2;
    op[0] = o0; op[1] = o1;
  }
}

extern "C" void kernel_launch(void* const* d_in, const int* in_sizes, int n_in,
                              void* d_out, int out_size, void* d_ws, size_t ws_size,
                              hipStream_t stream) {
  const float* x0 = (const float*)d_in[0];
  const float* x1 = (const float*)d_in[1];
  const float* x2 = (const float*)d_in[2];
  const int* rows0 = (const int*)d_in[3];
  const int* cols0 = (const int*)d_in[4];
  const int* rows1 = (const int*)d_in[5];
  const int* cols1 = (const int*)d_in[6];
  const int* rows2 = (const int*)d_in[7];
  const int* cols2 = (const int*)d_in[8];
  const float* W1 = (const float*)d_in[9];
  const float* b1 = (const float*)d_in[10];
  const float* W2 = (const float*)d_in[11];
  const float* b2 = (const float*)d_in[12];
  const float* W3 = (const float*)d_in[13];
  const float* b3 = (const float*)d_in[14];
  const float* W4 = (const float*)d_in[15];
  const float* b4 = (const float*)d_in[16];
  const float* a1_w = (const float*)d_in[17];
  const float* a1_b = (const float*)d_in[18];
  const float* a2_w = (const float*)d_in[19];
  const float* a2_b = (const float*)d_in[20];
  float* out = (float*)d_out;

  char* ws = (char*)d_ws;
  size_t off = 0;
  auto alloc = [&](size_t bytes) -> void* {
    void* p = ws + off;
    off = (off + bytes + 255) & ~(size_t)255;
    return p;
  };
  ushort_t* XJ = (ushort_t*)alloc((size_t)NTc * D * 2);       // bf16 xj concat
  ushort_t* XI0 = (ushort_t*)alloc((size_t)N0c * D * 2);      // bf16 xi_0
  ushort_t* Wt = (ushort_t*)alloc((size_t)4 * 65536 * 2);     // bf16 W, granule-major
  float* AJ = (float*)alloc((size_t)NTc * 4);
  float* ai = (float*)alloc((size_t)N0c * 4);
  int* counts = (int*)alloc((size_t)N0c * 4);
  int* row_start = (int*)alloc((size_t)(N0c + 1) * 4);
  int* fill = (int*)alloc((size_t)N0c * 4);
  int* bsum = (int*)alloc((size_t)SCAN_BLOCKS * 4);
  int* boff = (int*)alloc((size_t)SCAN_BLOCKS * 4);
  int* edge_dst = (int*)alloc((size_t)ETc * 4);
  (void)ws_size; (void)in_sizes; (void)n_in; (void)out_size;

  hipLaunchKernelGGL(init_kernel, dim3((NTc + 255) / 256), dim3(256), 0, stream,
                     ai, AJ, counts, a1_b, a2_b);
  hipLaunchKernelGGL(wconv_kernel, dim3(32, 4), dim3(256), 0, stream,
                     W1, W2, W3, W4, Wt);
  hipLaunchKernelGGL(hist_kernel, dim3((ETc + 255) / 256), dim3(256), 0, stream,
                     rows0, rows1, rows2, counts);
  hipLaunchKernelGGL(blocksum_kernel, dim3(SCAN_BLOCKS), dim3(256), 0, stream,
                     counts, bsum);
  hipLaunchKernelGGL(scantop_kernel, dim3(1), dim3(256), 0, stream,
                     bsum, boff, row_start);
  hipLaunchKernelGGL(emit_kernel, dim3(SCAN_BLOCKS), dim3(256), 0, stream,
                     counts, boff, row_start, fill);
  hipLaunchKernelGGL(scatter_kernel, dim3((ETc + 255) / 256), dim3(256), 0, stream,
                     rows0, cols0, rows1, cols1, rows2, cols2, fill, edge_dst);

  hipLaunchKernelGGL(gemm_mfma, dim3((N0c + 63) / 64), dim3(256), 0, stream,
                     x0, Wt + 0 * 65536, b1, a1_w, ai, XI0, N0c);
  hipLaunchKernelGGL(gemm_mfma, dim3((N0c + 63) / 64), dim3(256), 0, stream,
                     x0, Wt + 1 * 65536, b2, a2_w, AJ, XJ, N0c);
  hipLaunchKernelGGL(gemm_mfma, dim3((N1c + 63) / 64), dim3(256), 0, stream,
                     x1, Wt + 2 * 65536, b3, a2_w, AJ + N0c, XJ + (size_t)N0c * D, N1c);
  hipLaunchKernelGGL(gemm_mfma, dim3((N2c + 63) / 64), dim3(256), 0, stream,
                     x2, Wt + 3 * 65536, b4, a2_w, AJ + N0c + N1c,
                     XJ + (size_t)(N0c + N1c) * D, N2c);

  hipLaunchKernelGGL(aggregate_kernel, dim3(N0c), dim3(64), 0, stream,
                     XI0, XJ, ai, AJ, row_start, edge_dst, out);
}